// Round 2
// baseline (338.973 us; speedup 1.0000x reference)
//
#include <hip/hip_runtime.h>

#define Bdim 32
#define Sdim 512
#define Hdim 1024
#define NEG 10
#define ROWS (Bdim * (Sdim - 1))   // 16352

__global__ __launch_bounds__(256) void infonce_loss_kernel(
    const float* __restrict__ enc,     // (B, S, H)
    const float* __restrict__ emb,     // (B, S, H)
    const int*   __restrict__ negidx,  // (B, S-1, NEG)
    const float* __restrict__ temp,    // scalar
    float* __restrict__ out)           // scalar (pre-zeroed)
{
    const int row = blockIdx.x;            // 0..ROWS-1
    const int b   = row / (Sdim - 1);
    const int s   = row % (Sdim - 1);
    const int tid = threadIdx.x;           // 0..255, each owns 4 floats of H

    const float4* pred = (const float4*)(enc + (size_t)(b * Sdim + s) * Hdim);
    const float4* pos  = (const float4*)(emb + (size_t)(b * Sdim + s + 1) * Hdim);

    float4 p = pred[tid];
    float4 q = pos[tid];

    // acc[0]=pos dot, acc[1]=|p|^2, acc[2]=|q|^2, acc[3..12]=neg dots
    float acc[13];
    acc[0] = p.x * q.x + p.y * q.y + p.z * q.z + p.w * q.w;
    acc[1] = p.x * p.x + p.y * p.y + p.z * p.z + p.w * p.w;
    acc[2] = q.x * q.x + q.y * q.y + q.z * q.z + q.w * q.w;

    const int* ni = negidx + (size_t)row * NEG;   // block-uniform address
#pragma unroll
    for (int n = 0; n < NEG; ++n) {
        int idx = ni[n];
        idx += (idx >= b * Sdim) ? Sdim : 0;      // skip own batch rows
        const float4* neg = (const float4*)(emb + (size_t)idx * Hdim);
        float4 v = neg[tid];
        acc[3 + n] = p.x * v.x + p.y * v.y + p.z * v.z + p.w * v.w;
    }

    // wave64 shuffle reduction for all 13 accumulators
#pragma unroll
    for (int k = 0; k < 13; ++k) {
        float v = acc[k];
#pragma unroll
        for (int off = 32; off > 0; off >>= 1)
            v += __shfl_down(v, off, 64);
        acc[k] = v;
    }

    __shared__ float lds[4][13];
    const int wave = tid >> 6;
    const int lane = tid & 63;
    if (lane == 0) {
#pragma unroll
        for (int k = 0; k < 13; ++k) lds[wave][k] = acc[k];
    }
    __syncthreads();

    if (tid == 0) {
        float r[13];
#pragma unroll
        for (int k = 0; k < 13; ++k)
            r[k] = lds[0][k] + lds[1][k] + lds[2][k] + lds[3][k];

        const float t    = *temp;
        const float invt = 1.0f / t;
        const float pn = fmaxf(sqrtf(r[1]), 1e-8f);
        const float qn = fmaxf(sqrtf(r[2]), 1e-8f);
        const float pos_score = r[0] / (pn * qn) * invt;

        float m = pos_score;
        float negs[NEG];
#pragma unroll
        for (int n = 0; n < NEG; ++n) {
            negs[n] = r[3 + n] * invt;
            m = fmaxf(m, negs[n]);
        }
        float sum = expf(pos_score - m);
#pragma unroll
        for (int n = 0; n < NEG; ++n) sum += expf(negs[n] - m);
        const float lse = m + logf(sum);

        atomicAdd(out, (lse - pos_score) * (1.0f / (float)ROWS));
    }
}

extern "C" void kernel_launch(void* const* d_in, const int* in_sizes, int n_in,
                              void* d_out, int out_size, void* d_ws, size_t ws_size,
                              hipStream_t stream) {
    const float* enc    = (const float*)d_in[0];
    const float* emb    = (const float*)d_in[1];
    const int*   negidx = (const int*)d_in[2];
    const float* temp   = (const float*)d_in[3];
    float* out = (float*)d_out;

    hipMemsetAsync(out, 0, sizeof(float) * out_size, stream);
    infonce_loss_kernel<<<ROWS, 256, 0, stream>>>(enc, emb, negidx, temp, out);
}

// Round 4
// 214.864 us; speedup vs baseline: 1.5776x; 1.5776x over previous
//
#include <hip/hip_runtime.h>

#define Bdim 32
#define Sdim 512
#define Hdim 1024
#define NEG 10
#define ROWS (Bdim * (Sdim - 1))   // 16352
#define WAVES_PER_BLOCK 8          // 512 threads, 8 rows per block

__global__ __launch_bounds__(512) void infonce_wave_kernel(
    const float* __restrict__ enc,     // (B, S, H)
    const float* __restrict__ emb,     // (B, S, H)
    const int*   __restrict__ negidx,  // (B, S-1, NEG)
    const float* __restrict__ temp,    // scalar
    float* __restrict__ out)           // scalar (pre-zeroed)
{
    const int tid  = threadIdx.x;
    const int wave = tid >> 6;
    const int lane = tid & 63;
    const int row  = blockIdx.x * WAVES_PER_BLOCK + wave;   // 0..ROWS-1
    const int b    = row / (Sdim - 1);
    const int s    = row % (Sdim - 1);

    // lane owns float4 elements at [lane + 64*j], j=0..3  (coalesced 1KB/instr)
    const float4* pred = (const float4*)(enc + (size_t)(b * Sdim + s) * Hdim);
    const float4* pos  = (const float4*)(emb + (size_t)(b * Sdim + s + 1) * Hdim);

    // load all 10 neg indices first so gather addresses are ready early
    const int* ni = negidx + (size_t)row * NEG;
    int idx[NEG];
#pragma unroll
    for (int n = 0; n < NEG; ++n) {
        int v = ni[n];
        idx[n] = v + ((v >= b * Sdim) ? Sdim : 0);
    }

    float4 p[4], q[4];
#pragma unroll
    for (int j = 0; j < 4; ++j) p[j] = pred[lane + 64 * j];
#pragma unroll
    for (int j = 0; j < 4; ++j) q[j] = pos[lane + 64 * j];

    // acc[0]=pos dot, acc[1]=|p|^2, acc[2]=|q|^2, acc[3..12]=neg dots
    float acc[13];
#pragma unroll
    for (int k = 0; k < 13; ++k) acc[k] = 0.0f;

#pragma unroll
    for (int j = 0; j < 4; ++j) {
        acc[0] += p[j].x * q[j].x + p[j].y * q[j].y + p[j].z * q[j].z + p[j].w * q[j].w;
        acc[1] += p[j].x * p[j].x + p[j].y * p[j].y + p[j].z * p[j].z + p[j].w * p[j].w;
        acc[2] += q[j].x * q[j].x + q[j].y * q[j].y + q[j].z * q[j].z + q[j].w * q[j].w;
    }

#pragma unroll
    for (int n = 0; n < NEG; ++n) {
        const float4* neg = (const float4*)(emb + (size_t)idx[n] * Hdim);
        float4 v0 = neg[lane];
        float4 v1 = neg[lane + 64];
        float4 v2 = neg[lane + 128];
        float4 v3 = neg[lane + 192];
        float d = 0.0f;
        d += p[0].x * v0.x + p[0].y * v0.y + p[0].z * v0.z + p[0].w * v0.w;
        d += p[1].x * v1.x + p[1].y * v1.y + p[1].z * v1.z + p[1].w * v1.w;
        d += p[2].x * v2.x + p[2].y * v2.y + p[2].z * v2.z + p[2].w * v2.w;
        d += p[3].x * v3.x + p[3].y * v3.y + p[3].z * v3.z + p[3].w * v3.w;
        acc[3 + n] = d;
    }

    // wave64 butterfly reduction, no cross-wave sync needed
#pragma unroll
    for (int k = 0; k < 13; ++k) {
        float v = acc[k];
#pragma unroll
        for (int off = 1; off < 64; off <<= 1)
            v += __shfl_xor(v, off, 64);
        acc[k] = v;
    }

    __shared__ float wloss[WAVES_PER_BLOCK];
    if (lane == 0) {
        const float t    = *temp;
        const float invt = 1.0f / t;
        const float pn = fmaxf(sqrtf(acc[1]), 1e-8f);
        const float qn = fmaxf(sqrtf(acc[2]), 1e-8f);
        const float pos_score = acc[0] / (pn * qn) * invt;

        float m = pos_score;
        float negs[NEG];
#pragma unroll
        for (int n = 0; n < NEG; ++n) {
            negs[n] = acc[3 + n] * invt;
            m = fmaxf(m, negs[n]);
        }
        float sum = expf(pos_score - m);
#pragma unroll
        for (int n = 0; n < NEG; ++n) sum += expf(negs[n] - m);
        const float lse = m + logf(sum);

        wloss[wave] = (lse - pos_score) * (1.0f / (float)ROWS);
    }
    __syncthreads();

    if (tid == 0) {
        float sum = 0.0f;
#pragma unroll
        for (int w = 0; w < WAVES_PER_BLOCK; ++w) sum += wloss[w];
        atomicAdd(out, sum);
    }
}

extern "C" void kernel_launch(void* const* d_in, const int* in_sizes, int n_in,
                              void* d_out, int out_size, void* d_ws, size_t ws_size,
                              hipStream_t stream) {
    const float* enc    = (const float*)d_in[0];
    const float* emb    = (const float*)d_in[1];
    const int*   negidx = (const int*)d_in[2];
    const float* temp   = (const float*)d_in[3];
    float* out = (float*)d_out;

    hipMemsetAsync(out, 0, sizeof(float) * out_size, stream);
    infonce_wave_kernel<<<ROWS / WAVES_PER_BLOCK, 512, 0, stream>>>(enc, emb, negidx, temp, out);
}